// Round 14
// baseline (5294.246 us; speedup 1.0000x reference)
//
#include <hip/hip_runtime.h>
#include <hip/hip_bf16.h>

#define Tz  512
#define Hz  512
#define BHz (256*512)
#define NBLK 192
#define HB4 (BHz/4)      // ull words per h buffer

typedef __bf16 bf16x8 __attribute__((ext_vector_type(8)));
typedef float  f32x4  __attribute__((ext_vector_type(4)));
typedef unsigned u32x4 __attribute__((ext_vector_type(4)));
typedef unsigned long long ull;

#define MFMA16(A,B,C) __builtin_amdgcn_mfma_f32_16x16x32_bf16(A,B,C,0,0,0)

__device__ __forceinline__ float sigf(float x){ return 1.0f/(1.0f+__expf(-x)); }
__device__ __forceinline__ float tanhf_(float x){ return 2.0f/(1.0f+__expf(-2.0f*x)) - 1.0f; }

__device__ __forceinline__ unsigned cload32(const unsigned* p){
    return __hip_atomic_load(p, __ATOMIC_RELAXED, __HIP_MEMORY_SCOPE_AGENT);
}
__device__ __forceinline__ void cstore32(unsigned* p, unsigned v){
    __hip_atomic_store(p, v, __ATOMIC_RELAXED, __HIP_MEMORY_SCOPE_AGENT);
}

// ---- pack weights as MFMA A-operand frags (W^T), gate-interleaved (r5-r9 verified) ----
__global__ void pack_w1(const float* __restrict__ w, __bf16* __restrict__ out){
    int idx = blockIdx.x*256 + threadIdx.x;   // 1,048,576 = 128*16*64*8
    int i = idx & 7, lane = (idx>>3)&63, kb = (idx>>9)&15, jt = idx>>13;
    int k  = kb*32 + (lane>>4)*8 + i;
    int m  = lane & 15;
    int col = (m&3)*512 + jt*4 + (m>>2);
    out[idx] = (__bf16)w[k*2048 + col];
}
__global__ void pack_w2(const float* __restrict__ wih, const float* __restrict__ whh,
                        __bf16* __restrict__ out){
    int idx = blockIdx.x*256 + threadIdx.x;   // 2,097,152 = 128*32*64*8
    int i = idx & 7, lane = (idx>>3)&63, kb = (idx>>9)&31, jt = idx>>14;
    int k  = kb*32 + (lane>>4)*8 + i;
    int m  = lane & 15;
    int col = (m&3)*512 + jt*4 + (m>>2);
    float val = (k < 512) ? wih[k*2048 + col] : whh[(k-512)*2048 + col];
    out[idx] = (__bf16)val;
}
__global__ void pack_bias(const float* a, const float* b, const float* c, const float* d,
                          float* b1s, float* b2s){
    int i = blockIdx.x*256 + threadIdx.x;
    if (i < 2048){ b1s[i] = a[i]+b[i]; b2s[i] = c[i]+d[i]; }
}

// ---- staging: PLAIN CACHED 16B loads (normal read path; L3-served after inv) ----
__device__ __forceinline__ void issue8(u32x4* r, const ull* src, int tid){
    #pragma unroll
    for (int i = 0; i < 8; ++i){
        int c = tid + 256*i;
        const ull* p = src + (size_t)(c>>6)*128 + (size_t)(c&63)*2;
        asm volatile("global_load_dwordx4 %0, %1, off" : "=v"(r[i]) : "v"(p) : "memory");
    }
}
__device__ __forceinline__ void write8(bf16x8* sh, const u32x4* r, int tid){
    #pragma unroll
    for (int i = 0; i < 8; ++i){
        int c = tid + 256*i;
        union { u32x4 u; bf16x8 v; } U; U.u = r[i];
        sh[c ^ ((c>>6) & 7)] = U.v;
    }
}
#define DRAIN() do { asm volatile("s_waitcnt vmcnt(0)" ::: "memory"); \
                     __builtin_amdgcn_sched_barrier(0); } while(0)

// acquire fence: invalidates L1/L2 so the plain loads below observe the
// producers' L3-committed (sc0 sc1) stores. Lingering stale lines are killed
// here; every post-fence fill is flag-gated => fresh. One per phase.
#define ACQ() __builtin_amdgcn_fence(__ATOMIC_ACQUIRE, "agent")

// ---- coherent stores (commit to L3; drained before flag publish) ----
__device__ __forceinline__ void cstore128(ull* p, ull lo, ull hi){
    union { ull q2[2]; u32x4 u; } S; S.q2[0] = lo; S.q2[1] = hi;
    asm volatile("global_store_dwordx4 %0, %1, off sc0 sc1" :: "v"(p), "v"(S.u) : "memory");
}

// ---- wave-0-only flag polls (coherent), raw barrier ----
__device__ __forceinline__ void pollL1(const unsigned* fb, int tid, unsigned tgt){
    if (tid < 8){ const unsigned* fp = fb + tid*16;
        while (cload32(fp) < tgt) {} }
    __builtin_amdgcn_s_barrier();
}
__device__ __forceinline__ void pollL2(const unsigned* fb, int tid, unsigned tgt){
    if (tid < 16){ const unsigned* fp = fb + (8+tid)*16;
        while (cload32(fp) < tgt) {} }
    __builtin_amdgcn_s_barrier();
}

// ---- persistent 2-layer LSTM; 8 bands x 24 blocks; flag dataflow; 4-deep h rings ----
__launch_bounds__(256, 1)
__global__ void lstm_persistent(const float* __restrict__ x,
                                const float* __restrict__ wih1,
                                const float* __restrict__ b1s,
                                const float* __restrict__ b2s,
                                const __bf16* __restrict__ w1p,
                                const __bf16* __restrict__ w2p,
                                __bf16* __restrict__ h1b,   // 4 x [B][H]
                                __bf16* __restrict__ h2b,   // 4 x [B][H]
                                unsigned* __restrict__ flags)
{
    __shared__ bf16x8 sh[4096];   // 64 KB
    const int bid = blockIdx.x;
    const int g   = bid & 7;
    const int t   = bid >> 3;     // 0..23
    unsigned* fbase = flags + g*384;

    const int tid  = threadIdx.x;
    const int v    = tid >> 6;
    const int lane = tid & 63;
    const int llo  = lane & 15, lhi = lane >> 4;
    const int sw   = llo & 7;

    const ull* h1u = (const ull*)h1b;
    const ull* h2u = (const ull*)h2b;
    const size_t bandoff = (size_t)g*32*128;

    if (t < 8){
        // ---------------- layer 1: wave = 32 rows x jt0..jt0+3 ----------------
        const int jt0 = t*16 + v*4;
        bf16x8 wf[4][16];
        #pragma unroll
        for (int m = 0; m < 4; ++m)
            #pragma unroll
            for (int kb = 0; kb < 16; ++kb)
                wf[m][kb] = *reinterpret_cast<const bf16x8*>(
                    w1p + ((size_t)((jt0+m)*16 + kb)*64 + lane)*8);
        float wa[4][4], wb[4][4], bb[4][4];
        #pragma unroll
        for (int m = 0; m < 4; ++m)
            #pragma unroll
            for (int q = 0; q < 4; ++q){
                int col = q*512 + (jt0+m)*4 + lhi;
                wa[m][q] = wih1[col]; wb[m][q] = wih1[2048 + col]; bb[m][q] = b1s[col];
            }
        const float2* x2 = reinterpret_cast<const float2*>(x);
        float c1[4][2] = {{0,0},{0,0},{0,0},{0,0}};

        for (int p = 0; p < Tz; ++p){
            pollL1(fbase, tid, (unsigned)p);                    // mates' h1[p-1] ready
            ACQ();                                              // inv L1/L2 once per phase
            u32x4 rA[8];
            issue8(rA, h1u + (size_t)((p+3)&3)*HB4 + bandoff, tid);
            DRAIN();
            write8(sh, rA, tid);
            __syncthreads();
            f32x4 acc[4][2];
            #pragma unroll
            for (int m = 0; m < 4; ++m){ acc[m][0] = (f32x4){0,0,0,0}; acc[m][1] = (f32x4){0,0,0,0}; }
            #pragma unroll
            for (int nt = 0; nt < 2; ++nt){
                const int base = (nt*16 + llo) << 6;
                #pragma unroll
                for (int kb = 0; kb < 16; ++kb){
                    bf16x8 bf = sh[(base + kb*4 + lhi) ^ sw];
                    acc[0][nt] = MFMA16(wf[0][kb], bf, acc[0][nt]);
                    acc[1][nt] = MFMA16(wf[1][kb], bf, acc[1][nt]);
                    acc[2][nt] = MFMA16(wf[2][kb], bf, acc[2][nt]);
                    acc[3][nt] = MFMA16(wf[3][kb], bf, acc[3][nt]);
                }
            }
            ull pkk[2][4];
            #pragma unroll
            for (int nt = 0; nt < 2; ++nt){
                int row = g*32 + nt*16 + llo;
                float2 xv = x2[(size_t)row*Tz + p];
                #pragma unroll
                for (int m = 0; m < 4; ++m){
                    float gi = acc[m][nt][0] + xv.x*wa[m][0] + xv.y*wb[m][0] + bb[m][0];
                    float gf = acc[m][nt][1] + xv.x*wa[m][1] + xv.y*wb[m][1] + bb[m][1];
                    float gg = acc[m][nt][2] + xv.x*wa[m][2] + xv.y*wb[m][2] + bb[m][2];
                    float go = acc[m][nt][3] + xv.x*wa[m][3] + xv.y*wb[m][3] + bb[m][3];
                    float cn = sigf(gf)*c1[m][nt] + sigf(gi)*tanhf_(gg);
                    c1[m][nt] = cn;
                    __bf16 hv = (__bf16)(sigf(go)*tanhf_(cn));
                    unsigned hb_;
                    { union { __bf16 b; unsigned short s; } C; C.b = hv; hb_ = C.s; }
                    unsigned s1 = __shfl(hb_, llo+16, 64);
                    unsigned s2 = __shfl(hb_, llo+32, 64);
                    unsigned s3 = __shfl(hb_, llo+48, 64);
                    pkk[nt][m] = (ull)hb_ | ((ull)s1<<16) | ((ull)s2<<32) | ((ull)s3<<48);
                }
            }
            pollL2(fbase, tid, (p >= 3) ? (unsigned)(p-3) : 0u); // anti-dep on buf p&3
            ull* h1n = (ull*)h1b + (size_t)(p&3)*HB4;
            if (lane < 16){
                #pragma unroll
                for (int nt = 0; nt < 2; ++nt){
                    int row = g*32 + nt*16 + llo;
                    ull* dst = h1n + (size_t)row*128 + jt0;
                    cstore128(dst,     pkk[nt][0], pkk[nt][1]);
                    cstore128(dst + 2, pkk[nt][2], pkk[nt][3]);
                }
            }
            __syncthreads();                                     // drains all waves' stores
            if (tid == 0) cstore32(fbase + t*16, (unsigned)(p+1));
        }
    } else {
        // ---------------- layer 2: wave = 32 rows x jt0..jt0+1, K=1024 ----------------
        const int u   = t - 8;               // 0..15
        const int jt0 = u*8 + v*2;
        bf16x8 wf[2][32];
        #pragma unroll
        for (int m = 0; m < 2; ++m)
            #pragma unroll
            for (int kb = 0; kb < 32; ++kb)
                wf[m][kb] = *reinterpret_cast<const bf16x8*>(
                    w2p + ((size_t)((jt0+m)*32 + kb)*64 + lane)*8);
        float bb2[2][4];
        #pragma unroll
        for (int m = 0; m < 2; ++m)
            #pragma unroll
            for (int q = 0; q < 4; ++q)
                bb2[m][q] = b2s[q*512 + (jt0+m)*4 + lhi];
        float c2[2][2] = {{0,0},{0,0}};

        for (int q = 1; q <= Tz; ++q){
            pollL2(fbase, tid, (unsigned)(q-1));                 // mates' h2[q-2] ready
            ACQ();                                               // inv once; all later fills flag-gated
            u32x4 rB[8];
            issue8(rB, h2u + (size_t)((q+2)&3)*HB4 + bandoff, tid);   // h2[q-2] in flight
            pollL1(fbase, tid, (unsigned)q);                     // fresh h1[q-1]; overlaps rB
            u32x4 rA[8];
            issue8(rA, h1u + (size_t)((q+3)&3)*HB4 + bandoff, tid);
            DRAIN();
            write8(sh,        rA, tid);
            write8(sh + 2048, rB, tid);
            __syncthreads();
            f32x4 acc[2][2];
            acc[0][0]=(f32x4){0,0,0,0}; acc[0][1]=(f32x4){0,0,0,0};
            acc[1][0]=(f32x4){0,0,0,0}; acc[1][1]=(f32x4){0,0,0,0};
            #pragma unroll
            for (int nt = 0; nt < 2; ++nt){
                const int base = (nt*16 + llo) << 6;
                #pragma unroll
                for (int kb = 0; kb < 16; ++kb){
                    bf16x8 bf = sh[(base + kb*4 + lhi) ^ sw];
                    acc[0][nt] = MFMA16(wf[0][kb], bf, acc[0][nt]);
                    acc[1][nt] = MFMA16(wf[1][kb], bf, acc[1][nt]);
                }
                #pragma unroll
                for (int kb = 16; kb < 32; ++kb){
                    bf16x8 bf = sh[2048 + ((base + (kb-16)*4 + lhi) ^ sw)];
                    acc[0][nt] = MFMA16(wf[0][kb], bf, acc[0][nt]);
                    acc[1][nt] = MFMA16(wf[1][kb], bf, acc[1][nt]);
                }
            }
            ull* h2n = (ull*)h2b + (size_t)((q+3)&3)*HB4;   // h2[q-1]
            #pragma unroll
            for (int nt = 0; nt < 2; ++nt){
                int row = g*32 + nt*16 + llo;
                ull pk[2];
                #pragma unroll
                for (int m = 0; m < 2; ++m){
                    float gi = acc[m][nt][0] + bb2[m][0];
                    float gf = acc[m][nt][1] + bb2[m][1];
                    float gg = acc[m][nt][2] + bb2[m][2];
                    float go = acc[m][nt][3] + bb2[m][3];
                    float cn = sigf(gf)*c2[m][nt] + sigf(gi)*tanhf_(gg);
                    c2[m][nt] = cn;
                    __bf16 hv = (__bf16)(sigf(go)*tanhf_(cn));
                    unsigned hb_;
                    { union { __bf16 b; unsigned short s; } C; C.b = hv; hb_ = C.s; }
                    unsigned s1 = __shfl(hb_, llo+16, 64);
                    unsigned s2 = __shfl(hb_, llo+32, 64);
                    unsigned s3 = __shfl(hb_, llo+48, 64);
                    pk[m] = (ull)hb_ | ((ull)s1<<16) | ((ull)s2<<32) | ((ull)s3<<48);
                }
                if (lane < 16){
                    ull* dst = h2n + (size_t)row*128 + jt0;
                    cstore128(dst, pk[0], pk[1]);
                }
            }
            __syncthreads();                                     // drains stores
            if (tid == 0) cstore32(fbase + t*16, (unsigned)q);
        }
    }
}

// ---- final logits + softmax ----
__global__ void logits_softmax(const __bf16* __restrict__ h2, const float* __restrict__ fcw,
                               const float* __restrict__ fcb, float* __restrict__ out)
{
    int row = blockIdx.x;
    int lane = threadIdx.x;
    float acc[11];
    #pragma unroll
    for (int o = 0; o < 11; ++o) acc[o] = 0.f;
    for (int it = 0; it < 8; ++it){
        int jj = it*64 + lane;
        float hv = (float)h2[row*512 + jj];
        #pragma unroll
        for (int o = 0; o < 11; ++o) acc[o] += hv * fcw[jj*11 + o];
    }
    #pragma unroll
    for (int o = 0; o < 11; ++o)
        for (int s = 32; s >= 1; s >>= 1) acc[o] += __shfl_xor(acc[o], s, 64);
    float m = -1e30f;
    #pragma unroll
    for (int o = 0; o < 11; ++o){ acc[o] += fcb[o]; m = fmaxf(m, acc[o]); }
    float ssum = 0.f;
    #pragma unroll
    for (int o = 0; o < 11; ++o){ acc[o] = __expf(acc[o] - m); ssum += acc[o]; }
    float inv = 1.0f/ssum;
    if (lane < 11) out[row*11 + lane] = acc[lane]*inv;
}

extern "C" void kernel_launch(void* const* d_in, const int* in_sizes, int n_in,
                              void* d_out, int out_size, void* d_ws, size_t ws_size,
                              hipStream_t stream)
{
    const float* x    = (const float*)d_in[0];
    const float* wih1 = (const float*)d_in[1];
    const float* whh1 = (const float*)d_in[2];
    const float* bih1 = (const float*)d_in[3];
    const float* bhh1 = (const float*)d_in[4];
    const float* wih2 = (const float*)d_in[5];
    const float* whh2 = (const float*)d_in[6];
    const float* bih2 = (const float*)d_in[7];
    const float* bhh2 = (const float*)d_in[8];
    const float* fcw  = (const float*)d_in[9];
    const float* fcb  = (const float*)d_in[10];
    float* out = (float*)d_out;

    char* p = (char*)d_ws;
    __bf16* w1p = (__bf16*)p;  p += (size_t)512*2048*2;   // 2 MB
    __bf16* w2p = (__bf16*)p;  p += (size_t)1024*2048*2;  // 4 MB
    float*  b1s = (float*)p;   p += 2048*4;
    float*  b2s = (float*)p;   p += 2048*4;
    __bf16* h1b = (__bf16*)p;  p += (size_t)4*BHz*2;      // 1 MB (4-deep ring)
    __bf16* h2b = (__bf16*)p;  p += (size_t)4*BHz*2;      // 1 MB
    unsigned* flags = (unsigned*)p; p += 8*384*4;         // 12 KB

    (void)hipMemsetAsync(h1b, 0, (size_t)4*BHz*2, stream);
    (void)hipMemsetAsync(h2b, 0, (size_t)4*BHz*2, stream);
    (void)hipMemsetAsync(flags, 0, 8*384*4, stream);
    pack_w1 <<<4096, 256, 0, stream>>>(whh1, w1p);
    pack_w2 <<<8192, 256, 0, stream>>>(wih2, whh2, w2p);
    pack_bias<<<8,   256, 0, stream>>>(bih1, bhh1, bih2, bhh2, b1s, b2s);

    lstm_persistent<<<NBLK, 256, 0, stream>>>(x, wih1, b1s, b2s, w1p, w2p, h1b, h2b, flags);

    // h2[T-1] lives in ring buffer 3 (511 & 3 == 3)
    logits_softmax<<<256, 64, 0, stream>>>(h2b + (size_t)3*BHz, fcw, fcb, out);
}

// Round 16
// 3132.799 us; speedup vs baseline: 1.6899x; 1.6899x over previous
//
#include <hip/hip_runtime.h>
#include <hip/hip_bf16.h>

#define Tz  512
#define Hz  512
#define BHz (256*512)
#define NBLK 192
#define HB4 (BHz/4)      // ull words per h buffer

typedef __bf16 bf16x8 __attribute__((ext_vector_type(8)));
typedef float  f32x4  __attribute__((ext_vector_type(4)));
typedef unsigned u32x4 __attribute__((ext_vector_type(4)));
typedef unsigned long long ull;

#define MFMA16(A,B,C) __builtin_amdgcn_mfma_f32_16x16x32_bf16(A,B,C,0,0,0)

__device__ __forceinline__ float sigf(float x){ return 1.0f/(1.0f+__expf(-x)); }
__device__ __forceinline__ float tanhf_(float x){ return 2.0f/(1.0f+__expf(-2.0f*x)) - 1.0f; }

__device__ __forceinline__ unsigned cload32(const unsigned* p){
    return __hip_atomic_load(p, __ATOMIC_RELAXED, __HIP_MEMORY_SCOPE_AGENT);
}
__device__ __forceinline__ void cstore32(unsigned* p, unsigned v){
    __hip_atomic_store(p, v, __ATOMIC_RELAXED, __HIP_MEMORY_SCOPE_AGENT);
}

// ---- pack weights as MFMA A-operand frags (W^T), gate-interleaved (r5-r9 verified) ----
__global__ void pack_w1(const float* __restrict__ w, __bf16* __restrict__ out){
    int idx = blockIdx.x*256 + threadIdx.x;   // 1,048,576 = 128*16*64*8
    int i = idx & 7, lane = (idx>>3)&63, kb = (idx>>9)&15, jt = idx>>13;
    int k  = kb*32 + (lane>>4)*8 + i;
    int m  = lane & 15;
    int col = (m&3)*512 + jt*4 + (m>>2);
    out[idx] = (__bf16)w[k*2048 + col];
}
__global__ void pack_w2(const float* __restrict__ wih, const float* __restrict__ whh,
                        __bf16* __restrict__ out){
    int idx = blockIdx.x*256 + threadIdx.x;   // 2,097,152 = 128*32*64*8
    int i = idx & 7, lane = (idx>>3)&63, kb = (idx>>9)&31, jt = idx>>14;
    int k  = kb*32 + (lane>>4)*8 + i;
    int m  = lane & 15;
    int col = (m&3)*512 + jt*4 + (m>>2);
    float val = (k < 512) ? wih[k*2048 + col] : whh[(k-512)*2048 + col];
    out[idx] = (__bf16)val;
}
__global__ void pack_bias(const float* a, const float* b, const float* c, const float* d,
                          float* b1s, float* b2s){
    int i = blockIdx.x*256 + threadIdx.x;
    if (i < 2048){ b1s[i] = a[i]+b[i]; b2s[i] = c[i]+d[i]; }
}

// ---- 16B coherent staging: issue 8 dwordx4 (L1/L2-bypass), drain once, LDS-write swizzled ----
__device__ __forceinline__ void issue8(u32x4* r, const ull* src, int tid){
    #pragma unroll
    for (int i = 0; i < 8; ++i){
        int c = tid + 256*i;
        const ull* p = src + (size_t)(c>>6)*128 + (size_t)(c&63)*2;
        asm volatile("global_load_dwordx4 %0, %1, off sc0 sc1" : "=v"(r[i]) : "v"(p) : "memory");
    }
}
__device__ __forceinline__ void write8(bf16x8* sh, const u32x4* r, int tid){
    #pragma unroll
    for (int i = 0; i < 8; ++i){
        int c = tid + 256*i;
        union { u32x4 u; bf16x8 v; } U; U.u = r[i];
        sh[c ^ ((c>>6) & 7)] = U.v;
    }
}
#define DRAIN() do { asm volatile("s_waitcnt vmcnt(0)" ::: "memory"); \
                     __builtin_amdgcn_sched_barrier(0); } while(0)

__device__ __forceinline__ void cstore128(ull* p, ull lo, ull hi){
    union { ull q2[2]; u32x4 u; } S; S.q2[0] = lo; S.q2[1] = hi;
    asm volatile("global_store_dwordx4 %0, %1, off sc0 sc1" :: "v"(p), "v"(S.u) : "memory");
}

// ---- wave-0-only flag polls (other waves keep loads in flight), raw barrier ----
__device__ __forceinline__ void pollL1(const unsigned* fbase, int tid, unsigned tgt){
    if (tid < 8){ const unsigned* fp = fbase + tid*16;
        while (cload32(fp) < tgt) {} }
    __builtin_amdgcn_s_barrier();
}
__device__ __forceinline__ void pollL2(const unsigned* fbase, int tid, unsigned tgt){
    if (tid < 16){ const unsigned* fp = fbase + (8+tid)*16;
        while (cload32(fp) < tgt) {} }
    __builtin_amdgcn_s_barrier();
}

// ---- persistent 2-layer LSTM; 8 bands x 24 blocks; flag dataflow; 4-deep h rings ----
__launch_bounds__(256, 1)
__global__ void lstm_persistent(const float* __restrict__ x,
                                const float* __restrict__ wih1,
                                const float* __restrict__ b1s,
                                const float* __restrict__ b2s,
                                const __bf16* __restrict__ w1p,
                                const __bf16* __restrict__ w2p,
                                __bf16* __restrict__ h1b,   // 4 x [B][H]
                                __bf16* __restrict__ h2b,   // 4 x [B][H]
                                unsigned* __restrict__ flags)
{
    __shared__ bf16x8 sh[4096];   // 64 KB
    const int bid = blockIdx.x;
    const int g   = bid & 7;
    const int t   = bid >> 3;     // 0..23
    unsigned* fbase = flags + g*384;

    const int tid  = threadIdx.x;
    const int v    = tid >> 6;
    const int lane = tid & 63;
    const int llo  = lane & 15, lhi = lane >> 4;
    const int sw   = llo & 7;

    const ull* h1u = (const ull*)h1b;
    const ull* h2u = (const ull*)h2b;
    const size_t bandoff = (size_t)g*32*128;

    if (t < 8){
        // ---------------- layer 1: wave = 32 rows x jt0..jt0+3 ----------------
        const int jt0 = t*16 + v*4;
        bf16x8 wf[4][16];
        #pragma unroll
        for (int m = 0; m < 4; ++m)
            #pragma unroll
            for (int kb = 0; kb < 16; ++kb)
                wf[m][kb] = *reinterpret_cast<const bf16x8*>(
                    w1p + ((size_t)((jt0+m)*16 + kb)*64 + lane)*8);
        float wa[4][4], wb[4][4], bb[4][4];
        #pragma unroll
        for (int m = 0; m < 4; ++m)
            #pragma unroll
            for (int q = 0; q < 4; ++q){
                int col = q*512 + (jt0+m)*4 + lhi;
                wa[m][q] = wih1[col]; wb[m][q] = wih1[2048 + col]; bb[m][q] = b1s[col];
            }
        const float2* x2 = reinterpret_cast<const float2*>(x);
        float c1[4][2] = {{0,0},{0,0},{0,0},{0,0}};

        for (int p = 0; p < Tz; ++p){
            pollL1(fbase, tid, (unsigned)p);                    // mates' h1[p-1] ready
            u32x4 rA[8];
            issue8(rA, h1u + (size_t)((p+3)&3)*HB4 + bandoff, tid);
            DRAIN();
            write8(sh, rA, tid);
            __syncthreads();
            f32x4 acc[4][2];
            #pragma unroll
            for (int m = 0; m < 4; ++m){ acc[m][0] = (f32x4){0,0,0,0}; acc[m][1] = (f32x4){0,0,0,0}; }
            #pragma unroll
            for (int nt = 0; nt < 2; ++nt){
                const int base = (nt*16 + llo) << 6;
                #pragma unroll
                for (int kb = 0; kb < 16; ++kb){
                    bf16x8 bf = sh[(base + kb*4 + lhi) ^ sw];
                    acc[0][nt] = MFMA16(wf[0][kb], bf, acc[0][nt]);
                    acc[1][nt] = MFMA16(wf[1][kb], bf, acc[1][nt]);
                    acc[2][nt] = MFMA16(wf[2][kb], bf, acc[2][nt]);
                    acc[3][nt] = MFMA16(wf[3][kb], bf, acc[3][nt]);
                }
            }
            // gate math
            ull pkk[2][4];
            #pragma unroll
            for (int nt = 0; nt < 2; ++nt){
                int row = g*32 + nt*16 + llo;
                float2 xv = x2[(size_t)row*Tz + p];
                #pragma unroll
                for (int m = 0; m < 4; ++m){
                    float gi = acc[m][nt][0] + xv.x*wa[m][0] + xv.y*wb[m][0] + bb[m][0];
                    float gf = acc[m][nt][1] + xv.x*wa[m][1] + xv.y*wb[m][1] + bb[m][1];
                    float gg = acc[m][nt][2] + xv.x*wa[m][2] + xv.y*wb[m][2] + bb[m][2];
                    float go = acc[m][nt][3] + xv.x*wa[m][3] + xv.y*wb[m][3] + bb[m][3];
                    float cn = sigf(gf)*c1[m][nt] + sigf(gi)*tanhf_(gg);
                    c1[m][nt] = cn;
                    __bf16 hv = (__bf16)(sigf(go)*tanhf_(cn));
                    unsigned hb_;
                    { union { __bf16 b; unsigned short s; } C; C.b = hv; hb_ = C.s; }
                    unsigned s1 = __shfl(hb_, llo+16, 64);
                    unsigned s2 = __shfl(hb_, llo+32, 64);
                    unsigned s3 = __shfl(hb_, llo+48, 64);
                    pkk[nt][m] = (ull)hb_ | ((ull)s1<<16) | ((ull)s2<<32) | ((ull)s3<<48);
                }
            }
            pollL2(fbase, tid, (p >= 3) ? (unsigned)(p-3) : 0u); // anti-dep on buf p&3
            ull* h1n = (ull*)h1b + (size_t)(p&3)*HB4;
            if (lane < 16){
                #pragma unroll
                for (int nt = 0; nt < 2; ++nt){
                    int row = g*32 + nt*16 + llo;
                    ull* dst = h1n + (size_t)row*128 + jt0;
                    cstore128(dst,     pkk[nt][0], pkk[nt][1]);
                    cstore128(dst + 2, pkk[nt][2], pkk[nt][3]);
                }
            }
            __syncthreads();                                     // drains all waves' stores
            if (tid == 0) cstore32(fbase + t*16, (unsigned)(p+1));
        }
    } else {
        // ---------------- layer 2: wave = 32 rows x jt0..jt0+1, K=1024 ----------------
        const int u   = t - 8;               // 0..15
        const int jt0 = u*8 + v*2;
        bf16x8 wf[2][32];
        #pragma unroll
        for (int m = 0; m < 2; ++m)
            #pragma unroll
            for (int kb = 0; kb < 32; ++kb)
                wf[m][kb] = *reinterpret_cast<const bf16x8*>(
                    w2p + ((size_t)((jt0+m)*32 + kb)*64 + lane)*8);
        float bb2[2][4];
        #pragma unroll
        for (int m = 0; m < 2; ++m)
            #pragma unroll
            for (int q = 0; q < 4; ++q)
                bb2[m][q] = b2s[q*512 + (jt0+m)*4 + lhi];
        float c2[2][2] = {{0,0},{0,0}};

        for (int q = 1; q <= Tz; ++q){
            pollL2(fbase, tid, (unsigned)(q-1));                 // mates' h2[q-2] ready
            u32x4 rB[8];
            issue8(rB, h2u + (size_t)((q+2)&3)*HB4 + bandoff, tid);   // h2[q-2] (in flight)
            pollL1(fbase, tid, (unsigned)q);                     // fresh h1[q-1]; overlaps rB
            u32x4 rA[8];
            issue8(rA, h1u + (size_t)((q+3)&3)*HB4 + bandoff, tid);
            DRAIN();
            write8(sh,        rA, tid);
            write8(sh + 2048, rB, tid);
            __syncthreads();
            f32x4 acc[2][2];
            acc[0][0]=(f32x4){0,0,0,0}; acc[0][1]=(f32x4){0,0,0,0};
            acc[1][0]=(f32x4){0,0,0,0}; acc[1][1]=(f32x4){0,0,0,0};
            #pragma unroll
            for (int nt = 0; nt < 2; ++nt){
                const int base = (nt*16 + llo) << 6;
                #pragma unroll
                for (int kb = 0; kb < 16; ++kb){
                    bf16x8 bf = sh[(base + kb*4 + lhi) ^ sw];
                    acc[0][nt] = MFMA16(wf[0][kb], bf, acc[0][nt]);
                    acc[1][nt] = MFMA16(wf[1][kb], bf, acc[1][nt]);
                }
                #pragma unroll
                for (int kb = 16; kb < 32; ++kb){
                    bf16x8 bf = sh[2048 + ((base + (kb-16)*4 + lhi) ^ sw)];
                    acc[0][nt] = MFMA16(wf[0][kb], bf, acc[0][nt]);
                    acc[1][nt] = MFMA16(wf[1][kb], bf, acc[1][nt]);
                }
            }
            ull* h2n = (ull*)h2b + (size_t)((q+3)&3)*HB4;   // h2[q-1]
            #pragma unroll
            for (int nt = 0; nt < 2; ++nt){
                int row = g*32 + nt*16 + llo;
                ull pk[2];
                #pragma unroll
                for (int m = 0; m < 2; ++m){
                    float gi = acc[m][nt][0] + bb2[m][0];
                    float gf = acc[m][nt][1] + bb2[m][1];
                    float gg = acc[m][nt][2] + bb2[m][2];
                    float go = acc[m][nt][3] + bb2[m][3];
                    float cn = sigf(gf)*c2[m][nt] + sigf(gi)*tanhf_(gg);
                    c2[m][nt] = cn;
                    __bf16 hv = (__bf16)(sigf(go)*tanhf_(cn));
                    unsigned hb_;
                    { union { __bf16 b; unsigned short s; } C; C.b = hv; hb_ = C.s; }
                    unsigned s1 = __shfl(hb_, llo+16, 64);
                    unsigned s2 = __shfl(hb_, llo+32, 64);
                    unsigned s3 = __shfl(hb_, llo+48, 64);
                    pk[m] = (ull)hb_ | ((ull)s1<<16) | ((ull)s2<<32) | ((ull)s3<<48);
                }
                if (lane < 16){
                    ull* dst = h2n + (size_t)row*128 + jt0;
                    cstore128(dst, pk[0], pk[1]);
                }
            }
            __syncthreads();                                     // drains stores
            if (tid == 0) cstore32(fbase + t*16, (unsigned)q);
        }
    }
}

// ---- final logits + softmax ----
__global__ void logits_softmax(const __bf16* __restrict__ h2, const float* __restrict__ fcw,
                               const float* __restrict__ fcb, float* __restrict__ out)
{
    int row = blockIdx.x;
    int lane = threadIdx.x;
    float acc[11];
    #pragma unroll
    for (int o = 0; o < 11; ++o) acc[o] = 0.f;
    for (int it = 0; it < 8; ++it){
        int jj = it*64 + lane;
        float hv = (float)h2[row*512 + jj];
        #pragma unroll
        for (int o = 0; o < 11; ++o) acc[o] += hv * fcw[jj*11 + o];
    }
    #pragma unroll
    for (int o = 0; o < 11; ++o)
        for (int s = 32; s >= 1; s >>= 1) acc[o] += __shfl_xor(acc[o], s, 64);
    float m = -1e30f;
    #pragma unroll
    for (int o = 0; o < 11; ++o){ acc[o] += fcb[o]; m = fmaxf(m, acc[o]); }
    float ssum = 0.f;
    #pragma unroll
    for (int o = 0; o < 11; ++o){ acc[o] = __expf(acc[o] - m); ssum += acc[o]; }
    float inv = 1.0f/ssum;
    if (lane < 11) out[row*11 + lane] = acc[lane]*inv;
}

extern "C" void kernel_launch(void* const* d_in, const int* in_sizes, int n_in,
                              void* d_out, int out_size, void* d_ws, size_t ws_size,
                              hipStream_t stream)
{
    const float* x    = (const float*)d_in[0];
    const float* wih1 = (const float*)d_in[1];
    const float* whh1 = (const float*)d_in[2];
    const float* bih1 = (const float*)d_in[3];
    const float* bhh1 = (const float*)d_in[4];
    const float* wih2 = (const float*)d_in[5];
    const float* whh2 = (const float*)d_in[6];
    const float* bih2 = (const float*)d_in[7];
    const float* bhh2 = (const float*)d_in[8];
    const float* fcw  = (const float*)d_in[9];
    const float* fcb  = (const float*)d_in[10];
    float* out = (float*)d_out;

    char* p = (char*)d_ws;
    __bf16* w1p = (__bf16*)p;  p += (size_t)512*2048*2;   // 2 MB
    __bf16* w2p = (__bf16*)p;  p += (size_t)1024*2048*2;  // 4 MB
    float*  b1s = (float*)p;   p += 2048*4;
    float*  b2s = (float*)p;   p += 2048*4;
    __bf16* h1b = (__bf16*)p;  p += (size_t)4*BHz*2;      // 1 MB (4-deep ring)
    __bf16* h2b = (__bf16*)p;  p += (size_t)4*BHz*2;      // 1 MB
    unsigned* flags = (unsigned*)p; p += 8*384*4;         // 12 KB

    (void)hipMemsetAsync(h1b, 0, (size_t)4*BHz*2, stream);
    (void)hipMemsetAsync(h2b, 0, (size_t)4*BHz*2, stream);
    (void)hipMemsetAsync(flags, 0, 8*384*4, stream);
    pack_w1 <<<4096, 256, 0, stream>>>(whh1, w1p);
    pack_w2 <<<8192, 256, 0, stream>>>(wih2, whh2, w2p);
    pack_bias<<<8,   256, 0, stream>>>(bih1, bhh1, bih2, bhh2, b1s, b2s);

    lstm_persistent<<<NBLK, 256, 0, stream>>>(x, wih1, b1s, b2s, w1p, w2p, h1b, h2b, flags);

    // h2[T-1] lives in ring buffer 3 (511 & 3 == 3)
    logits_softmax<<<256, 64, 0, stream>>>(h2b + BHz*3, fcw, fcb, out);
}